// Round 1
// baseline (226.475 us; speedup 1.0000x reference)
//
#include <hip/hip_runtime.h>

// Problem: out = C @ h_a + A @ h_b  where
//   h_a = relu(x_a @ W_a + b_a), h_b = relu(x_b @ W_b + b_b)
//   A = scatter(edge_ab), B = scatter(edge_ba), d = 1/deg (0 where deg==0)
//   C = (A * d[None,:]) @ B
// Collapse: out = A @ ( d[:,None] * (B @ h_a) + h_b )

#define D_FEAT 128

// One block per output row; 128 threads = one column each.
__global__ __launch_bounds__(128) void gemm_relu(
    const float* __restrict__ x, const float* __restrict__ W,
    const float* __restrict__ b, float* __restrict__ h, int F) {
    const int row = blockIdx.x;
    const int col = threadIdx.x;  // 0..127
    extern __shared__ float xs[];  // F floats
    const float4* xr = (const float4*)(x + (size_t)row * F);
    float4* xs4 = (float4*)xs;
    for (int i = col; i < F / 4; i += 128) xs4[i] = xr[i];
    __syncthreads();
    float acc = b[col];
#pragma unroll 8
    for (int k = 0; k < F; ++k) acc = fmaf(xs[k], W[k * D_FEAT + col], acc);
    h[(size_t)row * D_FEAT + col] = fmaxf(acc, 0.0f);
}

// deg[j] += 1 for ab cols and ba rows
__global__ __launch_bounds__(256) void deg_count(
    const int* __restrict__ ab_col, const int* __restrict__ ba_row,
    float* __restrict__ deg, int E) {
    int e = blockIdx.x * blockDim.x + threadIdx.x;
    if (e < E) {
        atomicAdd(&deg[ab_col[e]], 1.0f);
        atomicAdd(&deg[ba_row[e]], 1.0f);
    }
}

// dst[dst_idx[e]] += src[src_idx[e]]   (per feature, one thread per (e, f))
__global__ __launch_bounds__(256) void scatter_add(
    const int* __restrict__ dst_idx, const int* __restrict__ src_idx,
    const float* __restrict__ src, float* __restrict__ dst, long long total) {
    long long g = (long long)blockIdx.x * blockDim.x + threadIdx.x;
    if (g >= total) return;
    int e = (int)(g >> 7);
    int f = (int)(g & 127);
    int di = dst_idx[e];
    int si = src_idx[e];
    atomicAdd(&dst[(size_t)di * D_FEAT + f], src[(size_t)si * D_FEAT + f]);
}

// t[j,:] = t[j,:] / max(deg[j],1) (0 if deg==0) + h_b[j,:]
__global__ __launch_bounds__(256) void finalize_u(
    float* __restrict__ t, const float* __restrict__ h_b,
    const float* __restrict__ deg, int total) {
    int g = blockIdx.x * blockDim.x + threadIdx.x;
    if (g >= total) return;
    int j = g >> 7;
    float dg = deg[j];
    float inv = dg > 0.0f ? 1.0f / dg : 0.0f;
    t[g] = inv * t[g] + h_b[g];
}

extern "C" void kernel_launch(void* const* d_in, const int* in_sizes, int n_in,
                              void* d_out, int out_size, void* d_ws, size_t ws_size,
                              hipStream_t stream) {
    const float* x_a = (const float*)d_in[0];
    const float* x_b = (const float*)d_in[1];
    const float* W_a = (const float*)d_in[2];
    const float* b_a = (const float*)d_in[3];
    const float* W_b = (const float*)d_in[4];
    const float* b_b = (const float*)d_in[5];
    const int* ei_ab = (const int*)d_in[6];  // [2, E] -> rows, cols
    const int* ei_ba = (const int*)d_in[7];

    const int D = in_sizes[3];            // 128
    const int Fa = in_sizes[2] / D;       // 512
    const int Na = in_sizes[0] / Fa;      // 4096
    const int Fb = in_sizes[4] / D;       // 512
    const int Nb = in_sizes[1] / Fb;      // 4096
    const int E = in_sizes[6] / 2;        // 131072

    const int* ab_row = ei_ab;
    const int* ab_col = ei_ab + E;
    const int* ba_row = ei_ba;
    const int* ba_col = ei_ba + E;

    // Workspace layout (f32)
    float* h_a = (float*)d_ws;                       // Na*D
    float* h_b = h_a + (size_t)Na * D;               // Nb*D
    float* t   = h_b + (size_t)Nb * D;               // Nb*D   (B @ h_a, then u)
    float* deg = t + (size_t)Nb * D;                 // Nb

    float* out = (float*)d_out;

    // Zero accumulators (graph-capturable async memsets)
    hipMemsetAsync(t, 0, (size_t)Nb * D * sizeof(float), stream);
    hipMemsetAsync(deg, 0, (size_t)Nb * sizeof(float), stream);
    hipMemsetAsync(out, 0, (size_t)out_size * sizeof(float), stream);

    // h_a = relu(x_a @ W_a + b_a); h_b likewise
    gemm_relu<<<Na, 128, Fa * sizeof(float), stream>>>(x_a, W_a, b_a, h_a, Fa);
    gemm_relu<<<Nb, 128, Fb * sizeof(float), stream>>>(x_b, W_b, b_b, h_b, Fb);

    // deg = colcount(A) + rowcount(B)
    deg_count<<<(E + 255) / 256, 256, 0, stream>>>(ab_col, ba_row, deg, E);

    // t = B @ h_a : for each ba edge (r, c): t[r] += h_a[c]
    long long total_e = (long long)E * D_FEAT;
    int blocks_e = (int)((total_e + 255) / 256);
    scatter_add<<<blocks_e, 256, 0, stream>>>(ba_row, ba_col, h_a, t, total_e);

    // t = d[:,None] * t + h_b
    int total_n = Nb * D_FEAT;
    finalize_u<<<(total_n + 255) / 256, 256, 0, stream>>>(t, h_b, deg, total_n);

    // out = A @ t : for each ab edge (i, j): out[i] += t[j]
    scatter_add<<<blocks_e, 256, 0, stream>>>(ab_row, ab_col, t, out, total_e);
}

// Round 2
// 151.561 us; speedup vs baseline: 1.4943x; 1.4943x over previous
//
#include <hip/hip_runtime.h>

// out = A @ ( d[:,None] * (B @ h_a) + h_b )
//   h_a = relu(x_a @ W_a + b_a), h_b = relu(x_b @ W_b + b_b)
//   A = scatter(edge_ab) [Na,Nb], B = scatter(edge_ba) [Nb,Na]
//   d[j] = 1/deg[j], deg = colcount(A) + rowcount(B), 0 where deg==0
// CSR-ized: no float atomics anywhere.

#define D_FEAT 128

// ---------------- GEMM: h = relu(x @ W + b), 8 rows/block ----------------
// 256 threads: rg = tid>>5 (row 0..7), cg = tid&31 (4 cols each)
__global__ __launch_bounds__(256) void gemm_relu8(
    const float* __restrict__ x, const float* __restrict__ W,
    const float* __restrict__ b, float* __restrict__ h, int F, int N) {
    extern __shared__ float xs[];  // [8][F]
    const int tid = threadIdx.x;
    const int row0 = blockIdx.x * 8;
    const int rg = tid >> 5;        // 0..7
    const int cg = tid & 31;        // 0..31 -> cols cg*4..cg*4+3

    // stage 8 rows of x (8*F floats, contiguous)
    const float4* xr4 = (const float4*)(x + (size_t)row0 * F);
    float4* xs4 = (float4*)xs;
    const int n4 = 2 * F;  // 8*F/4
    for (int i = tid; i < n4; i += 256) xs4[i] = xr4[i];
    __syncthreads();

    const float4* W4 = (const float4*)W;  // [F][32] float4
    float4 bb = W4[0];  // placeholder init (overwritten below)
    bb = ((const float4*)b)[cg];
    float a0 = bb.x, a1 = bb.y, a2 = bb.z, a3 = bb.w;

    const int xbase = rg * (F >> 2);
    for (int k0 = 0; k0 < F; k0 += 4) {
        float4 xv = xs4[xbase + (k0 >> 2)];
        float4 w0 = W4[(k0 + 0) * 32 + cg];
        float4 w1 = W4[(k0 + 1) * 32 + cg];
        float4 w2 = W4[(k0 + 2) * 32 + cg];
        float4 w3 = W4[(k0 + 3) * 32 + cg];
        a0 = fmaf(xv.x, w0.x, a0); a1 = fmaf(xv.x, w0.y, a1);
        a2 = fmaf(xv.x, w0.z, a2); a3 = fmaf(xv.x, w0.w, a3);
        a0 = fmaf(xv.y, w1.x, a0); a1 = fmaf(xv.y, w1.y, a1);
        a2 = fmaf(xv.y, w1.z, a2); a3 = fmaf(xv.y, w1.w, a3);
        a0 = fmaf(xv.z, w2.x, a0); a1 = fmaf(xv.z, w2.y, a1);
        a2 = fmaf(xv.z, w2.z, a2); a3 = fmaf(xv.z, w2.w, a3);
        a0 = fmaf(xv.w, w3.x, a0); a1 = fmaf(xv.w, w3.y, a1);
        a2 = fmaf(xv.w, w3.z, a2); a3 = fmaf(xv.w, w3.w, a3);
    }
    int row = row0 + rg;
    if (row < N) {
        float4 o;
        o.x = fmaxf(a0, 0.0f); o.y = fmaxf(a1, 0.0f);
        o.z = fmaxf(a2, 0.0f); o.w = fmaxf(a3, 0.0f);
        ((float4*)(h + (size_t)row * D_FEAT))[cg] = o;
    }
}

// ---------------- CSR build ----------------
__global__ __launch_bounds__(256) void count_edges(
    const int* __restrict__ ab_row, const int* __restrict__ ab_col,
    const int* __restrict__ ba_row,
    int* __restrict__ cnt_ab, int* __restrict__ cnt_ba,
    int* __restrict__ degc, int E) {
    int e = blockIdx.x * blockDim.x + threadIdx.x;
    if (e < E) {
        atomicAdd(&cnt_ab[ab_row[e]], 1);
        atomicAdd(&cnt_ba[ba_row[e]], 1);
        atomicAdd(&degc[ab_col[e]], 1);
    }
}

// exclusive scan of exactly 4096 ints, one block of 1024 threads
__global__ __launch_bounds__(1024) void scan4k(
    const int* __restrict__ cnt, int* __restrict__ start) {
    __shared__ int part[1024];
    int t = threadIdx.x;
    int base = t * 4;
    int a0 = cnt[base], a1 = cnt[base + 1], a2 = cnt[base + 2], a3 = cnt[base + 3];
    part[t] = a0 + a1 + a2 + a3;
    __syncthreads();
    for (int off = 1; off < 1024; off <<= 1) {
        int v = (t >= off) ? part[t - off] : 0;
        __syncthreads();
        part[t] += v;
        __syncthreads();
    }
    int ex = (t == 0) ? 0 : part[t - 1];
    start[base] = ex;
    start[base + 1] = ex + a0;
    start[base + 2] = ex + a0 + a1;
    start[base + 3] = ex + a0 + a1 + a2;
}

__global__ __launch_bounds__(256) void fill_csr(
    const int* __restrict__ row, const int* __restrict__ col,
    const int* __restrict__ start, int* __restrict__ cur,
    int* __restrict__ out_col, int E) {
    int e = blockIdx.x * blockDim.x + threadIdx.x;
    if (e < E) {
        int r = row[e];
        int p = atomicAdd(&cur[r], 1);
        out_col[start[r] + p] = col[e];
    }
}

// ---------------- gather-reduce: dst[r] = sum_{c in row r} src[c] ----------------
// one 64-lane wave per row, float2 per lane; optional epilogue:
//   NORM: dst[r] = acc * (1/deg[r] or 0) + addv[r]
__global__ __launch_bounds__(256) void gather_rows(
    const int* __restrict__ start, const int* __restrict__ cnt,
    const int* __restrict__ cols, const float* __restrict__ src,
    float* __restrict__ dst, const float* __restrict__ addv,
    const int* __restrict__ dg0, const int* __restrict__ dg1,
    int Nrow, int norm) {
    int w = threadIdx.x >> 6;
    int lane = threadIdx.x & 63;
    int r = blockIdx.x * 4 + w;
    if (r >= Nrow) return;
    int s = start[r];
    int end = s + cnt[r];
    const float2* s2 = (const float2*)src;
    float ax = 0.0f, ay = 0.0f;
    int e = s;
    for (; e + 3 < end; e += 4) {
        int c0 = cols[e], c1 = cols[e + 1], c2 = cols[e + 2], c3 = cols[e + 3];
        float2 v0 = s2[(size_t)c0 * 64 + lane];
        float2 v1 = s2[(size_t)c1 * 64 + lane];
        float2 v2 = s2[(size_t)c2 * 64 + lane];
        float2 v3 = s2[(size_t)c3 * 64 + lane];
        ax += v0.x + v1.x + v2.x + v3.x;
        ay += v0.y + v1.y + v2.y + v3.y;
    }
    for (; e < end; ++e) {
        int c = cols[e];
        float2 v = s2[(size_t)c * 64 + lane];
        ax += v.x; ay += v.y;
    }
    if (norm) {
        float dgf = (float)(dg0[r] + dg1[r]);
        float inv = dgf > 0.0f ? 1.0f / dgf : 0.0f;
        float2 hb = ((const float2*)addv)[(size_t)r * 64 + lane];
        ax = ax * inv + hb.x;
        ay = ay * inv + hb.y;
    }
    float2 o; o.x = ax; o.y = ay;
    ((float2*)dst)[(size_t)r * 64 + lane] = o;
}

extern "C" void kernel_launch(void* const* d_in, const int* in_sizes, int n_in,
                              void* d_out, int out_size, void* d_ws, size_t ws_size,
                              hipStream_t stream) {
    const float* x_a = (const float*)d_in[0];
    const float* x_b = (const float*)d_in[1];
    const float* W_a = (const float*)d_in[2];
    const float* b_a = (const float*)d_in[3];
    const float* W_b = (const float*)d_in[4];
    const float* b_b = (const float*)d_in[5];
    const int* ei_ab = (const int*)d_in[6];
    const int* ei_ba = (const int*)d_in[7];

    const int D = in_sizes[3];            // 128
    const int Fa = in_sizes[2] / D;       // 512
    const int Na = in_sizes[0] / Fa;      // 4096
    const int Fb = in_sizes[4] / D;       // 512
    const int Nb = in_sizes[1] / Fb;      // 4096
    const int E = in_sizes[6] / 2;        // 131072

    const int* ab_row = ei_ab;
    const int* ab_col = ei_ab + E;
    const int* ba_row = ei_ba;
    const int* ba_col = ei_ba + E;

    // ---- workspace layout ----
    char* p = (char*)d_ws;
    float* h_a = (float*)p; p += (size_t)Na * D * 4;
    float* h_b = (float*)p; p += (size_t)Nb * D * 4;
    float* u   = (float*)p; p += (size_t)Nb * D * 4;
    int* col_ab = (int*)p; p += (size_t)E * 4;
    int* col_ba = (int*)p; p += (size_t)E * 4;
    int* cnt_ab = (int*)p; p += (size_t)Na * 4;
    int* cnt_ba = (int*)p; p += (size_t)Nb * 4;
    int* degc   = (int*)p; p += (size_t)Nb * 4;
    int* start_ab = (int*)p; p += (size_t)Na * 4;
    int* start_ba = (int*)p; p += (size_t)Nb * 4;

    float* out = (float*)d_out;

    // zero counters
    hipMemsetAsync(cnt_ab, 0, (size_t)(Na + 2 * Nb) * 4, stream);  // cnt_ab,cnt_ba,degc contiguous

    // projections
    gemm_relu8<<<(Na + 7) / 8, 256, 8 * Fa * sizeof(float), stream>>>(x_a, W_a, b_a, h_a, Fa, Na);
    gemm_relu8<<<(Nb + 7) / 8, 256, 8 * Fb * sizeof(float), stream>>>(x_b, W_b, b_b, h_b, Fb, Nb);

    // CSR build
    int eb = (E + 255) / 256;
    count_edges<<<eb, 256, 0, stream>>>(ab_row, ab_col, ba_row, cnt_ab, cnt_ba, degc, E);
    scan4k<<<1, 1024, 0, stream>>>(cnt_ab, start_ab);
    scan4k<<<1, 1024, 0, stream>>>(cnt_ba, start_ba);
    hipMemsetAsync(cnt_ab, 0, (size_t)Na * 4, stream);
    hipMemsetAsync(cnt_ba, 0, (size_t)Nb * 4, stream);
    fill_csr<<<eb, 256, 0, stream>>>(ab_row, ab_col, start_ab, cnt_ab, col_ab, E);
    fill_csr<<<eb, 256, 0, stream>>>(ba_row, ba_col, start_ba, cnt_ba, col_ba, E);
    // after fill, cnt_* hold the per-row counts again

    // u = d * (B @ h_a) + h_b
    gather_rows<<<(Nb + 3) / 4, 256, 0, stream>>>(start_ba, cnt_ba, col_ba, h_a, u,
                                                  h_b, degc, cnt_ba, Nb, 1);
    // out = A @ u
    gather_rows<<<(Na + 3) / 4, 256, 0, stream>>>(start_ab, cnt_ab, col_ab, u, out,
                                                  (const float*)nullptr,
                                                  (const int*)nullptr, (const int*)nullptr,
                                                  Na, 0);
}

// Round 3
// 132.881 us; speedup vs baseline: 1.7043x; 1.1406x over previous
//
#include <hip/hip_runtime.h>

// out = A @ ( d[:,None] * (B @ h_a) + h_b )
//   h_a = relu(x_a @ W_a + b_a), h_b = relu(x_b @ W_b + b_b)
//   A = scatter(edge_ab) [Na,Nb], B = scatter(edge_ba) [Nb,Na]
//   d[j] = 1/deg[j], deg = colcount(A) + rowcount(B), 0 where deg==0
// CSR-ized: no float atomics anywhere.

#define D_FEAT 128

// ---------------- dual GEMM: h = relu(x @ W + b) for BOTH node types ----------
// 16 rows/block, 256 threads. thread = (rg 0..7, cg 0..31); computes rows
// {row0+rg, row0+rg+8} x cols {4cg..4cg+3}. No LDS: x loads are wave-broadcast
// (32 lanes share one address), W loads hit L1/L2.
__global__ __launch_bounds__(256) void gemm_relu_dual(
    const float* __restrict__ xa, const float* __restrict__ Wa,
    const float* __restrict__ ba_, float* __restrict__ ha,
    const float* __restrict__ xb, const float* __restrict__ Wb,
    const float* __restrict__ bb_, float* __restrict__ hb,
    int Fa, int Fb, int nblk_a) {
    int blk = blockIdx.x;
    const float *x, *W, *bv;
    float* h;
    int F;
    if (blk < nblk_a) { x = xa; W = Wa; bv = ba_; h = ha; F = Fa; }
    else { blk -= nblk_a; x = xb; W = Wb; bv = bb_; h = hb; F = Fb; }

    const int cg = threadIdx.x & 31;   // 4 cols: 4cg..4cg+3
    const int rg = threadIdx.x >> 5;   // 0..7
    const int row0 = blk * 16;
    const int r0 = row0 + rg;
    const int r1 = row0 + rg + 8;

    const float4* x0 = (const float4*)(x + (size_t)r0 * F);
    const float4* x1 = (const float4*)(x + (size_t)r1 * F);
    const float4* W4 = (const float4*)W;  // [F][32] float4

    float4 b4 = ((const float4*)bv)[cg];
    float a00 = b4.x, a01 = b4.y, a02 = b4.z, a03 = b4.w;
    float a10 = b4.x, a11 = b4.y, a12 = b4.z, a13 = b4.w;

#pragma unroll 4
    for (int k = 0; k < F; k += 4) {
        float4 xv0 = x0[k >> 2];
        float4 xv1 = x1[k >> 2];
        float4 w0 = W4[(k + 0) * 32 + cg];
        float4 w1 = W4[(k + 1) * 32 + cg];
        float4 w2 = W4[(k + 2) * 32 + cg];
        float4 w3 = W4[(k + 3) * 32 + cg];
        a00 = fmaf(xv0.x, w0.x, a00); a01 = fmaf(xv0.x, w0.y, a01);
        a02 = fmaf(xv0.x, w0.z, a02); a03 = fmaf(xv0.x, w0.w, a03);
        a10 = fmaf(xv1.x, w0.x, a10); a11 = fmaf(xv1.x, w0.y, a11);
        a12 = fmaf(xv1.x, w0.z, a12); a13 = fmaf(xv1.x, w0.w, a13);
        a00 = fmaf(xv0.y, w1.x, a00); a01 = fmaf(xv0.y, w1.y, a01);
        a02 = fmaf(xv0.y, w1.z, a02); a03 = fmaf(xv0.y, w1.w, a03);
        a10 = fmaf(xv1.y, w1.x, a10); a11 = fmaf(xv1.y, w1.y, a11);
        a12 = fmaf(xv1.y, w1.z, a12); a13 = fmaf(xv1.y, w1.w, a13);
        a00 = fmaf(xv0.z, w2.x, a00); a01 = fmaf(xv0.z, w2.y, a01);
        a02 = fmaf(xv0.z, w2.z, a02); a03 = fmaf(xv0.z, w2.w, a03);
        a10 = fmaf(xv1.z, w2.x, a10); a11 = fmaf(xv1.z, w2.y, a11);
        a12 = fmaf(xv1.z, w2.z, a12); a13 = fmaf(xv1.z, w2.w, a13);
        a00 = fmaf(xv0.w, w3.x, a00); a01 = fmaf(xv0.w, w3.y, a01);
        a02 = fmaf(xv0.w, w3.z, a02); a03 = fmaf(xv0.w, w3.w, a03);
        a10 = fmaf(xv1.w, w3.x, a10); a11 = fmaf(xv1.w, w3.y, a11);
        a12 = fmaf(xv1.w, w3.z, a12); a13 = fmaf(xv1.w, w3.w, a13);
    }
    float4 o0, o1;
    o0.x = fmaxf(a00, 0.0f); o0.y = fmaxf(a01, 0.0f);
    o0.z = fmaxf(a02, 0.0f); o0.w = fmaxf(a03, 0.0f);
    o1.x = fmaxf(a10, 0.0f); o1.y = fmaxf(a11, 0.0f);
    o1.z = fmaxf(a12, 0.0f); o1.w = fmaxf(a13, 0.0f);
    ((float4*)(h + (size_t)r0 * D_FEAT))[cg] = o0;
    ((float4*)(h + (size_t)r1 * D_FEAT))[cg] = o1;
}

// ---------------- CSR build ----------------
__global__ __launch_bounds__(256) void count_edges(
    const int* __restrict__ ab_row, const int* __restrict__ ab_col,
    const int* __restrict__ ba_row,
    int* __restrict__ cnt_ab, int* __restrict__ cnt_ba,
    int* __restrict__ degc, int E) {
    int e = blockIdx.x * blockDim.x + threadIdx.x;
    if (e < E) {
        atomicAdd(&cnt_ab[ab_row[e]], 1);
        atomicAdd(&cnt_ba[ba_row[e]], 1);
        atomicAdd(&degc[ab_col[e]], 1);
    }
}

// exclusive scan of exactly 4096 ints; block 0 -> (cntA,startA), block 1 -> (cntB,startB)
__global__ __launch_bounds__(1024) void scan4k_dual(
    const int* __restrict__ cntA, int* __restrict__ startA,
    const int* __restrict__ cntB, int* __restrict__ startB) {
    const int* cnt = blockIdx.x ? cntB : cntA;
    int* start = blockIdx.x ? startB : startA;
    __shared__ int part[1024];
    int t = threadIdx.x;
    int base = t * 4;
    int a0 = cnt[base], a1 = cnt[base + 1], a2 = cnt[base + 2], a3 = cnt[base + 3];
    part[t] = a0 + a1 + a2 + a3;
    __syncthreads();
    for (int off = 1; off < 1024; off <<= 1) {
        int v = (t >= off) ? part[t - off] : 0;
        __syncthreads();
        part[t] += v;
        __syncthreads();
    }
    int ex = (t == 0) ? 0 : part[t - 1];
    start[base] = ex;
    start[base + 1] = ex + a0;
    start[base + 2] = ex + a0 + a1;
    start[base + 3] = ex + a0 + a1 + a2;
}

__global__ __launch_bounds__(256) void fill_csr(
    const int* __restrict__ row, const int* __restrict__ col,
    const int* __restrict__ start, int* __restrict__ cur,
    int* __restrict__ out_col, int E) {
    int e = blockIdx.x * blockDim.x + threadIdx.x;
    if (e < E) {
        int r = row[e];
        int p = atomicAdd(&cur[r], 1);
        out_col[start[r] + p] = col[e];
    }
}

// ---------------- gather-reduce: dst[r] = sum_{c in row r} src[c] ----------------
// one 64-lane wave per row, float2 per lane; norm epilogue:
//   dst[r] = acc * (1/deg[r] or 0) + addv[r]
__global__ __launch_bounds__(256) void gather_rows(
    const int* __restrict__ start, const int* __restrict__ cnt,
    const int* __restrict__ cols, const float* __restrict__ src,
    float* __restrict__ dst, const float* __restrict__ addv,
    const int* __restrict__ dg0, const int* __restrict__ dg1,
    int Nrow, int norm) {
    int w = threadIdx.x >> 6;
    int lane = threadIdx.x & 63;
    int r = blockIdx.x * 4 + w;
    if (r >= Nrow) return;
    int s = start[r];
    int end = s + cnt[r];
    const float2* s2 = (const float2*)src;
    float ax = 0.0f, ay = 0.0f;
    int e = s;
    for (; e + 3 < end; e += 4) {
        int c0 = cols[e], c1 = cols[e + 1], c2 = cols[e + 2], c3 = cols[e + 3];
        float2 v0 = s2[(size_t)c0 * 64 + lane];
        float2 v1 = s2[(size_t)c1 * 64 + lane];
        float2 v2 = s2[(size_t)c2 * 64 + lane];
        float2 v3 = s2[(size_t)c3 * 64 + lane];
        ax += v0.x + v1.x + v2.x + v3.x;
        ay += v0.y + v1.y + v2.y + v3.y;
    }
    for (; e < end; ++e) {
        int c = cols[e];
        float2 v = s2[(size_t)c * 64 + lane];
        ax += v.x; ay += v.y;
    }
    if (norm) {
        float dgf = (float)(dg0[r] + dg1[r]);
        float inv = dgf > 0.0f ? 1.0f / dgf : 0.0f;
        float2 hb = ((const float2*)addv)[(size_t)r * 64 + lane];
        ax = ax * inv + hb.x;
        ay = ay * inv + hb.y;
    }
    float2 o; o.x = ax; o.y = ay;
    ((float2*)dst)[(size_t)r * 64 + lane] = o;
}

extern "C" void kernel_launch(void* const* d_in, const int* in_sizes, int n_in,
                              void* d_out, int out_size, void* d_ws, size_t ws_size,
                              hipStream_t stream) {
    const float* x_a = (const float*)d_in[0];
    const float* x_b = (const float*)d_in[1];
    const float* W_a = (const float*)d_in[2];
    const float* b_a = (const float*)d_in[3];
    const float* W_b = (const float*)d_in[4];
    const float* b_b = (const float*)d_in[5];
    const int* ei_ab = (const int*)d_in[6];
    const int* ei_ba = (const int*)d_in[7];

    const int D = in_sizes[3];            // 128
    const int Fa = in_sizes[2] / D;       // 512
    const int Na = in_sizes[0] / Fa;      // 4096
    const int Fb = in_sizes[4] / D;       // 512
    const int Nb = in_sizes[1] / Fb;      // 4096
    const int E = in_sizes[6] / 2;        // 131072

    const int* ab_row = ei_ab;
    const int* ab_col = ei_ab + E;
    const int* ba_row = ei_ba;
    const int* ba_col = ei_ba + E;

    // ---- workspace layout ----
    char* p = (char*)d_ws;
    float* h_a = (float*)p; p += (size_t)Na * D * 4;
    float* h_b = (float*)p; p += (size_t)Nb * D * 4;
    float* u   = (float*)p; p += (size_t)Nb * D * 4;
    int* col_ab = (int*)p; p += (size_t)E * 4;
    int* col_ba = (int*)p; p += (size_t)E * 4;
    // zeroed region (single memset): cnt_ab, cnt_ba, degc, cur_ab, cur_ba
    int* cnt_ab = (int*)p; p += (size_t)Na * 4;
    int* cnt_ba = (int*)p; p += (size_t)Nb * 4;
    int* degc   = (int*)p; p += (size_t)Nb * 4;
    int* cur_ab = (int*)p; p += (size_t)Na * 4;
    int* cur_ba = (int*)p; p += (size_t)Nb * 4;
    int* start_ab = (int*)p; p += (size_t)Na * 4;
    int* start_ba = (int*)p; p += (size_t)Nb * 4;

    float* out = (float*)d_out;

    // zero all counters in one shot (cnt_ab..cur_ba contiguous)
    hipMemsetAsync(cnt_ab, 0, (size_t)(2 * Na + 3 * Nb) * 4, stream);

    // both projections in one launch
    int nblk_a = Na / 16, nblk_b = Nb / 16;
    gemm_relu_dual<<<nblk_a + nblk_b, 256, 0, stream>>>(
        x_a, W_a, b_a, h_a, x_b, W_b, b_b, h_b, Fa, Fb, nblk_a);

    // CSR build
    int eb = (E + 255) / 256;
    count_edges<<<eb, 256, 0, stream>>>(ab_row, ab_col, ba_row, cnt_ab, cnt_ba, degc, E);
    scan4k_dual<<<2, 1024, 0, stream>>>(cnt_ab, start_ab, cnt_ba, start_ba);
    fill_csr<<<eb, 256, 0, stream>>>(ab_row, ab_col, start_ab, cur_ab, col_ab, E);
    fill_csr<<<eb, 256, 0, stream>>>(ba_row, ba_col, start_ba, cur_ba, col_ba, E);

    // u = d * (B @ h_a) + h_b
    gather_rows<<<(Nb + 3) / 4, 256, 0, stream>>>(start_ba, cnt_ba, col_ba, h_a, u,
                                                  h_b, degc, cnt_ba, Nb, 1);
    // out = A @ u
    gather_rows<<<(Na + 3) / 4, 256, 0, stream>>>(start_ab, cnt_ab, col_ab, u, out,
                                                  (const float*)nullptr,
                                                  (const int*)nullptr, (const int*)nullptr,
                                                  Na, 0);
}

// Round 5
// 86.970 us; speedup vs baseline: 2.6041x; 1.5279x over previous
//
#include <hip/hip_runtime.h>

// out = A @ ( d[:,None] * (B @ h_a) + h_b )
//   h_a = relu(x_a @ W_a + b_a), h_b = relu(x_b @ W_b + b_b)
//   A = scatter(edge_ab) [Na,Nb], B = scatter(edge_ba) [Nb,Na]
//   deg = colcount(A) + rowcount(B); d = 1/deg (0 where deg==0)
// Projections via bf16 MFMA 16x16x32; aggregation via CSR gather (no float atomics).

#define D_FEAT 128
#define F_IN 512

using short8 = __attribute__((ext_vector_type(8))) short;
using f32x4  = __attribute__((ext_vector_type(4))) float;

__device__ inline short f2bf(float f) {
    unsigned u = __builtin_bit_cast(unsigned, f);
    unsigned r = (u + 0x7FFFu + ((u >> 16) & 1u)) >> 16;
    return (short)r;
}

// ---------------- W pre-swizzle into MFMA B-fragment layout ----------------
// Wf layout: [t=0..15][c=0..7][lane=0..63][e=0..7] (shorts), where
//   k = t*32 + (lane>>4)*8 + e, col = c*16 + (lane&15)
__global__ __launch_bounds__(256) void w_prep(
    const float* __restrict__ Wa, const float* __restrict__ Wb,
    short* __restrict__ WfA, short* __restrict__ WfB) {
    int g = blockIdx.x * 256 + threadIdx.x;  // 0..16383
    const float* W = (g < 8192) ? Wa : Wb;
    short* Wf = (g < 8192) ? WfA : WfB;
    int i = g & 8191;
    int l = i & 63;
    int c = (i >> 6) & 7;
    int t = i >> 9;  // 0..15
    int col = c * 16 + (l & 15);
    int kbase = t * 32 + (l >> 4) * 8;
    short8 o;
#pragma unroll
    for (int e = 0; e < 8; ++e) o[e] = f2bf(W[(size_t)(kbase + e) * D_FEAT + col]);
    *(short8*)(Wf + (size_t)i * 8) = o;
}

// ---------------- dual MFMA GEMM: h = relu(x @ W + b) ----------------
// 16 rows/block, 256 thr = 4 waves; wave w owns K window [w*128, w*128+128).
// A loaded from f32 x and converted in-register; B from pre-swizzled Wf.
// Cross-wave reduce in LDS (stride 132 = conflict-free), bias+relu epilogue.
__global__ __launch_bounds__(256) void gemm_mfma_dual(
    const float* __restrict__ xa, const short* __restrict__ Wfa,
    const float* __restrict__ ba_, float* __restrict__ ha,
    const float* __restrict__ xb, const short* __restrict__ Wfb,
    const float* __restrict__ bb_, float* __restrict__ hb,
    int nblk_a) {
    int blk = blockIdx.x;
    const float* x; const short* Wf; const float* bias; float* h;
    if (blk < nblk_a) { x = xa; Wf = Wfa; bias = ba_; h = ha; }
    else { blk -= nblk_a; x = xb; Wf = Wfb; bias = bb_; h = hb; }
    const int row0 = blk * 16;
    const int tid = threadIdx.x;
    const int w = tid >> 6;
    const int l = tid & 63;
    const int lr = l & 15;   // A-row / C-col within tile
    const int lk = l >> 4;   // k-subgroup / C-row-group

    f32x4 acc[8];
#pragma unroll
    for (int c = 0; c < 8; ++c) acc[c] = (f32x4){0.f, 0.f, 0.f, 0.f};

    const float* xrow = x + (size_t)(row0 + lr) * F_IN;
#pragma unroll
    for (int ks = 0; ks < 4; ++ks) {
        const int t = w * 4 + ks;
        const int k0 = t * 32 + lk * 8;
        float4 xf0 = *(const float4*)(xrow + k0);
        float4 xf1 = *(const float4*)(xrow + k0 + 4);
        short8 afr;
        afr[0] = f2bf(xf0.x); afr[1] = f2bf(xf0.y);
        afr[2] = f2bf(xf0.z); afr[3] = f2bf(xf0.w);
        afr[4] = f2bf(xf1.x); afr[5] = f2bf(xf1.y);
        afr[6] = f2bf(xf1.z); afr[7] = f2bf(xf1.w);
        const short8* wfp = (const short8*)Wf + ((size_t)t * 8 * 64 + l);
#pragma unroll
        for (int c = 0; c < 8; ++c) {
            short8 bfr = wfp[c * 64];
            acc[c] = __builtin_amdgcn_mfma_f32_16x16x32_bf16(afr, bfr, acc[c], 0, 0, 0);
        }
    }

    __shared__ float red[4][16][132];
#pragma unroll
    for (int c = 0; c < 8; ++c)
#pragma unroll
        for (int r = 0; r < 4; ++r)
            red[w][lk * 4 + r][c * 16 + lr] = acc[c][r];
    __syncthreads();

#pragma unroll
    for (int q = 0; q < 2; ++q) {
        int fi = tid * 2 + q;          // 0..511
        int r = fi >> 5;               // 0..15
        int c4 = fi & 31;              // float4 col index
        float4 s0 = *(const float4*)&red[0][r][c4 * 4];
        float4 s1 = *(const float4*)&red[1][r][c4 * 4];
        float4 s2 = *(const float4*)&red[2][r][c4 * 4];
        float4 s3 = *(const float4*)&red[3][r][c4 * 4];
        float4 bv = ((const float4*)bias)[c4];
        float4 o;
        o.x = fmaxf(s0.x + s1.x + s2.x + s3.x + bv.x, 0.0f);
        o.y = fmaxf(s0.y + s1.y + s2.y + s3.y + bv.y, 0.0f);
        o.z = fmaxf(s0.z + s1.z + s2.z + s3.z + bv.z, 0.0f);
        o.w = fmaxf(s0.w + s1.w + s2.w + s3.w + bv.w, 0.0f);
        ((float4*)(h + (size_t)(row0 + r) * D_FEAT))[c4] = o;
    }
}

// ---------------- CSR build ----------------
__global__ __launch_bounds__(256) void count_edges(
    const int* __restrict__ ab_row, const int* __restrict__ ab_col,
    const int* __restrict__ ba_row,
    int* __restrict__ cnt_ab, int* __restrict__ cnt_ba,
    int* __restrict__ degc, int E) {
    int e = blockIdx.x * blockDim.x + threadIdx.x;
    if (e < E) {
        atomicAdd(&cnt_ab[ab_row[e]], 1);
        atomicAdd(&cnt_ba[ba_row[e]], 1);
        atomicAdd(&degc[ab_col[e]], 1);
    }
}

// exclusive scan of exactly 4096 ints; block 0 -> A, block 1 -> B
__global__ __launch_bounds__(1024) void scan4k_dual(
    const int* __restrict__ cntA, int* __restrict__ startA,
    const int* __restrict__ cntB, int* __restrict__ startB) {
    const int* cnt = blockIdx.x ? cntB : cntA;
    int* start = blockIdx.x ? startB : startA;
    __shared__ int part[1024];
    int t = threadIdx.x;
    int base = t * 4;
    int a0 = cnt[base], a1 = cnt[base + 1], a2 = cnt[base + 2], a3 = cnt[base + 3];
    part[t] = a0 + a1 + a2 + a3;
    __syncthreads();
    for (int off = 1; off < 1024; off <<= 1) {
        int v = (t >= off) ? part[t - off] : 0;
        __syncthreads();
        part[t] += v;
        __syncthreads();
    }
    int ex = (t == 0) ? 0 : part[t - 1];
    start[base] = ex;
    start[base + 1] = ex + a0;
    start[base + 2] = ex + a0 + a1;
    start[base + 3] = ex + a0 + a1 + a2;
}

// both CSR fills in one launch
__global__ __launch_bounds__(256) void fill_csr_dual(
    const int* __restrict__ ab_row, const int* __restrict__ ab_col,
    const int* __restrict__ ba_row, const int* __restrict__ ba_col,
    const int* __restrict__ start_ab, int* __restrict__ cur_ab, int* __restrict__ col_ab,
    const int* __restrict__ start_ba, int* __restrict__ cur_ba, int* __restrict__ col_ba,
    int Eab, int Eba) {
    int g = blockIdx.x * blockDim.x + threadIdx.x;
    if (g < Eab) {
        int r = ab_row[g];
        int p = atomicAdd(&cur_ab[r], 1);
        col_ab[start_ab[r] + p] = ab_col[g];
    } else if (g < Eab + Eba) {
        int e = g - Eab;
        int r = ba_row[e];
        int p = atomicAdd(&cur_ba[r], 1);
        col_ba[start_ba[r] + p] = ba_col[e];
    }
}

// ---------------- gather-reduce: dst[r] = sum_{c in row r} src[c] ----------------
// one 64-lane wave per row, float2 per lane, 8-deep unroll; norm epilogue:
//   dst[r] = acc * (1/deg[r] or 0) + addv[r]
__global__ __launch_bounds__(256) void gather_rows(
    const int* __restrict__ start, const int* __restrict__ cnt,
    const int* __restrict__ cols, const float* __restrict__ src,
    float* __restrict__ dst, const float* __restrict__ addv,
    const int* __restrict__ dg0, const int* __restrict__ dg1,
    int Nrow, int norm) {
    int w = threadIdx.x >> 6;
    int lane = threadIdx.x & 63;
    int r = blockIdx.x * 4 + w;
    if (r >= Nrow) return;
    int s = start[r];
    int end = s + cnt[r];
    const float2* s2 = (const float2*)src;
    float ax = 0.0f, ay = 0.0f;
    int e = s;
    for (; e + 7 < end; e += 8) {
        int c0 = cols[e],     c1 = cols[e + 1], c2 = cols[e + 2], c3 = cols[e + 3];
        int c4 = cols[e + 4], c5 = cols[e + 5], c6 = cols[e + 6], c7 = cols[e + 7];
        float2 v0 = s2[(size_t)c0 * 64 + lane];
        float2 v1 = s2[(size_t)c1 * 64 + lane];
        float2 v2 = s2[(size_t)c2 * 64 + lane];
        float2 v3 = s2[(size_t)c3 * 64 + lane];
        float2 v4 = s2[(size_t)c4 * 64 + lane];
        float2 v5 = s2[(size_t)c5 * 64 + lane];
        float2 v6 = s2[(size_t)c6 * 64 + lane];
        float2 v7 = s2[(size_t)c7 * 64 + lane];
        ax += (v0.x + v1.x) + (v2.x + v3.x) + ((v4.x + v5.x) + (v6.x + v7.x));
        ay += (v0.y + v1.y) + (v2.y + v3.y) + ((v4.y + v5.y) + (v6.y + v7.y));
    }
    for (; e < end; ++e) {
        int c = cols[e];
        float2 v = s2[(size_t)c * 64 + lane];
        ax += v.x; ay += v.y;
    }
    if (norm) {
        float dgf = (float)(dg0[r] + dg1[r]);
        float inv = dgf > 0.0f ? 1.0f / dgf : 0.0f;
        float2 hbv = ((const float2*)addv)[(size_t)r * 64 + lane];
        ax = ax * inv + hbv.x;
        ay = ay * inv + hbv.y;
    }
    float2 o; o.x = ax; o.y = ay;
    ((float2*)dst)[(size_t)r * 64 + lane] = o;
}

extern "C" void kernel_launch(void* const* d_in, const int* in_sizes, int n_in,
                              void* d_out, int out_size, void* d_ws, size_t ws_size,
                              hipStream_t stream) {
    const float* x_a = (const float*)d_in[0];
    const float* x_b = (const float*)d_in[1];
    const float* W_a = (const float*)d_in[2];
    const float* b_a = (const float*)d_in[3];
    const float* W_b = (const float*)d_in[4];
    const float* b_b = (const float*)d_in[5];
    const int* ei_ab = (const int*)d_in[6];
    const int* ei_ba = (const int*)d_in[7];

    const int D = in_sizes[3];            // 128
    const int Fa = in_sizes[2] / D;       // 512
    const int Na = in_sizes[0] / Fa;      // 4096
    const int Fb = in_sizes[4] / D;       // 512
    const int Nb = in_sizes[1] / Fb;      // 4096
    const int Eab = in_sizes[6] / 2;      // 131072
    const int Eba = in_sizes[7] / 2;      // 131072

    const int* ab_row = ei_ab;
    const int* ab_col = ei_ab + Eab;
    const int* ba_row = ei_ba;
    const int* ba_col = ei_ba + Eba;

    // ---- workspace layout ----
    char* p = (char*)d_ws;
    float* h_a = (float*)p; p += (size_t)Na * D * 4;
    float* h_b = (float*)p; p += (size_t)Nb * D * 4;
    float* u   = (float*)p; p += (size_t)Nb * D * 4;
    int* col_ab = (int*)p; p += (size_t)Eab * 4;
    int* col_ba = (int*)p; p += (size_t)Eba * 4;
    short* WfA = (short*)p; p += (size_t)Fa * D * 2;   // 128 KB
    short* WfB = (short*)p; p += (size_t)Fb * D * 2;
    // zeroed region (single memset): cnt_ab, cnt_ba, degc, cur_ab, cur_ba
    int* cnt_ab = (int*)p; p += (size_t)Na * 4;
    int* cnt_ba = (int*)p; p += (size_t)Nb * 4;
    int* degc   = (int*)p; p += (size_t)Nb * 4;
    int* cur_ab = (int*)p; p += (size_t)Na * 4;
    int* cur_ba = (int*)p; p += (size_t)Nb * 4;
    int* start_ab = (int*)p; p += (size_t)Na * 4;
    int* start_ba = (int*)p; p += (size_t)Nb * 4;

    float* out = (float*)d_out;

    hipMemsetAsync(cnt_ab, 0, (size_t)(2 * Na + 3 * Nb) * 4, stream);

    // W -> fragment layout (both)
    w_prep<<<64, 256, 0, stream>>>(W_a, W_b, WfA, WfB);

    // CSR build
    int eb = (Eab + 255) / 256;
    count_edges<<<eb, 256, 0, stream>>>(ab_row, ab_col, ba_row, cnt_ab, cnt_ba, degc, Eab);
    scan4k_dual<<<2, 1024, 0, stream>>>(cnt_ab, start_ab, cnt_ba, start_ba);
    fill_csr_dual<<<(Eab + Eba + 255) / 256, 256, 0, stream>>>(
        ab_row, ab_col, ba_row, ba_col,
        start_ab, cur_ab, col_ab, start_ba, cur_ba, col_ba, Eab, Eba);

    // projections (both) via MFMA
    int nblk_a = Na / 16, nblk_b = Nb / 16;
    gemm_mfma_dual<<<nblk_a + nblk_b, 256, 0, stream>>>(
        x_a, WfA, b_a, h_a, x_b, WfB, b_b, h_b, nblk_a);

    // u = d * (B @ h_a) + h_b
    gather_rows<<<(Nb + 3) / 4, 256, 0, stream>>>(start_ba, cnt_ba, col_ba, h_a, u,
                                                  h_b, degc, cnt_ba, Nb, 1);
    // out = A @ u
    gather_rows<<<(Na + 3) / 4, 256, 0, stream>>>(start_ab, cnt_ab, col_ab, u, out,
                                                  (const float*)nullptr,
                                                  (const int*)nullptr, (const int*)nullptr,
                                                  Na, 0);
}

// Round 6
// 84.068 us; speedup vs baseline: 2.6939x; 1.0345x over previous
//
#include <hip/hip_runtime.h>

// out = A @ ( d[:,None] * (B @ h_a) + h_b )
//   h_a = relu(x_a @ W_a + b_a), h_b = relu(x_b @ W_b + b_b)
//   A = scatter(edge_ab) [Na,Nb], B = scatter(edge_ba) [Nb,Na]
//   deg = colcount(A) + rowcount(B); d = 1/deg (0 where deg==0)
// Projections via bf16 MFMA 16x16x32; aggregation via CSR gather (no float atomics).
// NOTE: no hipMemsetAsync — it became a 43us fill dispatch (half the graph);
// counter zeroing is folded into w_prep (runs before count_edges in-stream).

#define D_FEAT 128
#define F_IN 512

using short8 = __attribute__((ext_vector_type(8))) short;
using f32x4  = __attribute__((ext_vector_type(4))) float;

__device__ inline short f2bf(float f) {
    unsigned u = __builtin_bit_cast(unsigned, f);
    unsigned r = (u + 0x7FFFu + ((u >> 16) & 1u)) >> 16;
    return (short)r;
}

// ---------------- W pre-swizzle into MFMA B-fragment layout + counter zero ----
// Wf layout: [t=0..15][c=0..7][lane=0..63][e=0..7] (shorts), where
//   k = t*32 + (lane>>4)*8 + e, col = c*16 + (lane&15)
__global__ __launch_bounds__(256) void w_prep(
    const float* __restrict__ Wa, const float* __restrict__ Wb,
    short* __restrict__ WfA, short* __restrict__ WfB,
    int* __restrict__ zero_region, int zero_n) {
    int g = blockIdx.x * 256 + threadIdx.x;  // 0..16383
    // zero the counter region (consumed by the NEXT kernel in stream order)
    for (int z = g; z < zero_n; z += 16384) zero_region[z] = 0;
    const float* W = (g < 8192) ? Wa : Wb;
    short* Wf = (g < 8192) ? WfA : WfB;
    int i = g & 8191;
    int l = i & 63;
    int c = (i >> 6) & 7;
    int t = i >> 9;  // 0..15
    int col = c * 16 + (l & 15);
    int kbase = t * 32 + (l >> 4) * 8;
    short8 o;
#pragma unroll
    for (int e = 0; e < 8; ++e) o[e] = f2bf(W[(size_t)(kbase + e) * D_FEAT + col]);
    *(short8*)(Wf + (size_t)i * 8) = o;
}

// ---------------- dual MFMA GEMM: h = relu(x @ W + b) ----------------
// 16 rows/block, 256 thr = 4 waves; wave w owns K window [w*128, w*128+128).
// A loaded from f32 x and converted in-register; B from pre-swizzled Wf.
// Cross-wave reduce in LDS (stride 132 = conflict-free), bias+relu epilogue.
__global__ __launch_bounds__(256) void gemm_mfma_dual(
    const float* __restrict__ xa, const short* __restrict__ Wfa,
    const float* __restrict__ ba_, float* __restrict__ ha,
    const float* __restrict__ xb, const short* __restrict__ Wfb,
    const float* __restrict__ bb_, float* __restrict__ hb,
    int nblk_a) {
    int blk = blockIdx.x;
    const float* x; const short* Wf; const float* bias; float* h;
    if (blk < nblk_a) { x = xa; Wf = Wfa; bias = ba_; h = ha; }
    else { blk -= nblk_a; x = xb; Wf = Wfb; bias = bb_; h = hb; }
    const int row0 = blk * 16;
    const int tid = threadIdx.x;
    const int w = tid >> 6;
    const int l = tid & 63;
    const int lr = l & 15;   // A-row / C-col within tile
    const int lk = l >> 4;   // k-subgroup / C-row-group

    f32x4 acc[8];
#pragma unroll
    for (int c = 0; c < 8; ++c) acc[c] = (f32x4){0.f, 0.f, 0.f, 0.f};

    const float* xrow = x + (size_t)(row0 + lr) * F_IN;
#pragma unroll
    for (int ks = 0; ks < 4; ++ks) {
        const int t = w * 4 + ks;
        const int k0 = t * 32 + lk * 8;
        float4 xf0 = *(const float4*)(xrow + k0);
        float4 xf1 = *(const float4*)(xrow + k0 + 4);
        short8 afr;
        afr[0] = f2bf(xf0.x); afr[1] = f2bf(xf0.y);
        afr[2] = f2bf(xf0.z); afr[3] = f2bf(xf0.w);
        afr[4] = f2bf(xf1.x); afr[5] = f2bf(xf1.y);
        afr[6] = f2bf(xf1.z); afr[7] = f2bf(xf1.w);
        const short8* wfp = (const short8*)Wf + ((size_t)t * 8 * 64 + l);
#pragma unroll
        for (int c = 0; c < 8; ++c) {
            short8 bfr = wfp[c * 64];
            acc[c] = __builtin_amdgcn_mfma_f32_16x16x32_bf16(afr, bfr, acc[c], 0, 0, 0);
        }
    }

    __shared__ float red[4][16][132];
#pragma unroll
    for (int c = 0; c < 8; ++c)
#pragma unroll
        for (int r = 0; r < 4; ++r)
            red[w][lk * 4 + r][c * 16 + lr] = acc[c][r];
    __syncthreads();

#pragma unroll
    for (int q = 0; q < 2; ++q) {
        int fi = tid * 2 + q;          // 0..511
        int r = fi >> 5;               // 0..15
        int c4 = fi & 31;              // float4 col index
        float4 s0 = *(const float4*)&red[0][r][c4 * 4];
        float4 s1 = *(const float4*)&red[1][r][c4 * 4];
        float4 s2 = *(const float4*)&red[2][r][c4 * 4];
        float4 s3 = *(const float4*)&red[3][r][c4 * 4];
        float4 bv = ((const float4*)bias)[c4];
        float4 o;
        o.x = fmaxf(s0.x + s1.x + s2.x + s3.x + bv.x, 0.0f);
        o.y = fmaxf(s0.y + s1.y + s2.y + s3.y + bv.y, 0.0f);
        o.z = fmaxf(s0.z + s1.z + s2.z + s3.z + bv.z, 0.0f);
        o.w = fmaxf(s0.w + s1.w + s2.w + s3.w + bv.w, 0.0f);
        ((float4*)(h + (size_t)(row0 + r) * D_FEAT))[c4] = o;
    }
}

// ---------------- CSR build ----------------
__global__ __launch_bounds__(256) void count_edges(
    const int* __restrict__ ab_row, const int* __restrict__ ab_col,
    const int* __restrict__ ba_row,
    int* __restrict__ cnt_ab, int* __restrict__ cnt_ba,
    int* __restrict__ degc, int E) {
    int e = blockIdx.x * blockDim.x + threadIdx.x;
    if (e < E) {
        atomicAdd(&cnt_ab[ab_row[e]], 1);
        atomicAdd(&cnt_ba[ba_row[e]], 1);
        atomicAdd(&degc[ab_col[e]], 1);
    }
}

// exclusive scan of exactly 4096 ints; block 0 -> A, block 1 -> B
__global__ __launch_bounds__(1024) void scan4k_dual(
    const int* __restrict__ cntA, int* __restrict__ startA,
    const int* __restrict__ cntB, int* __restrict__ startB) {
    const int* cnt = blockIdx.x ? cntB : cntA;
    int* start = blockIdx.x ? startB : startA;
    __shared__ int part[1024];
    int t = threadIdx.x;
    int base = t * 4;
    int a0 = cnt[base], a1 = cnt[base + 1], a2 = cnt[base + 2], a3 = cnt[base + 3];
    part[t] = a0 + a1 + a2 + a3;
    __syncthreads();
    for (int off = 1; off < 1024; off <<= 1) {
        int v = (t >= off) ? part[t - off] : 0;
        __syncthreads();
        part[t] += v;
        __syncthreads();
    }
    int ex = (t == 0) ? 0 : part[t - 1];
    start[base] = ex;
    start[base + 1] = ex + a0;
    start[base + 2] = ex + a0 + a1;
    start[base + 3] = ex + a0 + a1 + a2;
}

// both CSR fills in one launch
__global__ __launch_bounds__(256) void fill_csr_dual(
    const int* __restrict__ ab_row, const int* __restrict__ ab_col,
    const int* __restrict__ ba_row, const int* __restrict__ ba_col,
    const int* __restrict__ start_ab, int* __restrict__ cur_ab, int* __restrict__ col_ab,
    const int* __restrict__ start_ba, int* __restrict__ cur_ba, int* __restrict__ col_ba,
    int Eab, int Eba) {
    int g = blockIdx.x * blockDim.x + threadIdx.x;
    if (g < Eab) {
        int r = ab_row[g];
        int p = atomicAdd(&cur_ab[r], 1);
        col_ab[start_ab[r] + p] = ab_col[g];
    } else if (g < Eab + Eba) {
        int e = g - Eab;
        int r = ba_row[e];
        int p = atomicAdd(&cur_ba[r], 1);
        col_ba[start_ba[r] + p] = ba_col[e];
    }
}

// ---------------- gather-reduce: dst[r] = sum_{c in row r} src[c] ----------------
// one 64-lane wave per row, float2 per lane, 8-deep unroll; norm epilogue:
//   dst[r] = acc * (1/deg[r] or 0) + addv[r]
__global__ __launch_bounds__(256) void gather_rows(
    const int* __restrict__ start, const int* __restrict__ cnt,
    const int* __restrict__ cols, const float* __restrict__ src,
    float* __restrict__ dst, const float* __restrict__ addv,
    const int* __restrict__ dg0, const int* __restrict__ dg1,
    int Nrow, int norm) {
    int w = threadIdx.x >> 6;
    int lane = threadIdx.x & 63;
    int r = blockIdx.x * 4 + w;
    if (r >= Nrow) return;
    int s = start[r];
    int end = s + cnt[r];
    const float2* s2 = (const float2*)src;
    float ax = 0.0f, ay = 0.0f;
    int e = s;
    for (; e + 7 < end; e += 8) {
        int c0 = cols[e],     c1 = cols[e + 1], c2 = cols[e + 2], c3 = cols[e + 3];
        int c4 = cols[e + 4], c5 = cols[e + 5], c6 = cols[e + 6], c7 = cols[e + 7];
        float2 v0 = s2[(size_t)c0 * 64 + lane];
        float2 v1 = s2[(size_t)c1 * 64 + lane];
        float2 v2 = s2[(size_t)c2 * 64 + lane];
        float2 v3 = s2[(size_t)c3 * 64 + lane];
        float2 v4 = s2[(size_t)c4 * 64 + lane];
        float2 v5 = s2[(size_t)c5 * 64 + lane];
        float2 v6 = s2[(size_t)c6 * 64 + lane];
        float2 v7 = s2[(size_t)c7 * 64 + lane];
        ax += (v0.x + v1.x) + (v2.x + v3.x) + ((v4.x + v5.x) + (v6.x + v7.x));
        ay += (v0.y + v1.y) + (v2.y + v3.y) + ((v4.y + v5.y) + (v6.y + v7.y));
    }
    for (; e < end; ++e) {
        int c = cols[e];
        float2 v = s2[(size_t)c * 64 + lane];
        ax += v.x; ay += v.y;
    }
    if (norm) {
        float dgf = (float)(dg0[r] + dg1[r]);
        float inv = dgf > 0.0f ? 1.0f / dgf : 0.0f;
        float2 hbv = ((const float2*)addv)[(size_t)r * 64 + lane];
        ax = ax * inv + hbv.x;
        ay = ay * inv + hbv.y;
    }
    float2 o; o.x = ax; o.y = ay;
    ((float2*)dst)[(size_t)r * 64 + lane] = o;
}

extern "C" void kernel_launch(void* const* d_in, const int* in_sizes, int n_in,
                              void* d_out, int out_size, void* d_ws, size_t ws_size,
                              hipStream_t stream) {
    const float* x_a = (const float*)d_in[0];
    const float* x_b = (const float*)d_in[1];
    const float* W_a = (const float*)d_in[2];
    const float* b_a = (const float*)d_in[3];
    const float* W_b = (const float*)d_in[4];
    const float* b_b = (const float*)d_in[5];
    const int* ei_ab = (const int*)d_in[6];
    const int* ei_ba = (const int*)d_in[7];

    const int D = in_sizes[3];            // 128
    const int Fa = in_sizes[2] / D;       // 512
    const int Na = in_sizes[0] / Fa;      // 4096
    const int Fb = in_sizes[4] / D;       // 512
    const int Nb = in_sizes[1] / Fb;      // 4096
    const int Eab = in_sizes[6] / 2;      // 131072
    const int Eba = in_sizes[7] / 2;      // 131072

    const int* ab_row = ei_ab;
    const int* ab_col = ei_ab + Eab;
    const int* ba_row = ei_ba;
    const int* ba_col = ei_ba + Eba;

    // ---- workspace layout ----
    char* p = (char*)d_ws;
    float* h_a = (float*)p; p += (size_t)Na * D * 4;
    float* h_b = (float*)p; p += (size_t)Nb * D * 4;
    float* u   = (float*)p; p += (size_t)Nb * D * 4;
    int* col_ab = (int*)p; p += (size_t)Eab * 4;
    int* col_ba = (int*)p; p += (size_t)Eba * 4;
    short* WfA = (short*)p; p += (size_t)Fa * D * 2;   // 128 KB
    short* WfB = (short*)p; p += (size_t)Fb * D * 2;
    // zeroed region (by w_prep): cnt_ab, cnt_ba, degc, cur_ab, cur_ba (contiguous)
    int* cnt_ab = (int*)p; p += (size_t)Na * 4;
    int* cnt_ba = (int*)p; p += (size_t)Nb * 4;
    int* degc   = (int*)p; p += (size_t)Nb * 4;
    int* cur_ab = (int*)p; p += (size_t)Na * 4;
    int* cur_ba = (int*)p; p += (size_t)Nb * 4;
    int* start_ab = (int*)p; p += (size_t)Na * 4;
    int* start_ba = (int*)p; p += (size_t)Nb * 4;

    float* out = (float*)d_out;

    // W -> fragment layout (both) + zero counters (in-stream before count_edges)
    w_prep<<<64, 256, 0, stream>>>(W_a, W_b, WfA, WfB, cnt_ab, 2 * Na + 3 * Nb);

    // CSR build
    int eb = (Eab + 255) / 256;
    count_edges<<<eb, 256, 0, stream>>>(ab_row, ab_col, ba_row, cnt_ab, cnt_ba, degc, Eab);
    scan4k_dual<<<2, 1024, 0, stream>>>(cnt_ab, start_ab, cnt_ba, start_ba);
    fill_csr_dual<<<(Eab + Eba + 255) / 256, 256, 0, stream>>>(
        ab_row, ab_col, ba_row, ba_col,
        start_ab, cur_ab, col_ab, start_ba, cur_ba, col_ba, Eab, Eba);

    // projections (both) via MFMA
    int nblk_a = Na / 16, nblk_b = Nb / 16;
    gemm_mfma_dual<<<nblk_a + nblk_b, 256, 0, stream>>>(
        x_a, WfA, b_a, h_a, x_b, WfB, b_b, h_b, nblk_a);

    // u = d * (B @ h_a) + h_b
    gather_rows<<<(Nb + 3) / 4, 256, 0, stream>>>(start_ba, cnt_ba, col_ba, h_a, u,
                                                  h_b, degc, cnt_ba, Nb, 1);
    // out = A @ u
    gather_rows<<<(Na + 3) / 4, 256, 0, stream>>>(start_ab, cnt_ab, col_ab, u, out,
                                                  (const float*)nullptr,
                                                  (const int*)nullptr, (const int*)nullptr,
                                                  Na, 0);
}

// Round 7
// 59.937 us; speedup vs baseline: 3.7785x; 1.4026x over previous
//
#include <hip/hip_runtime.h>

// out = A @ ( d[:,None] * (B @ h_a) + h_b )
//   h_a = relu(x_a @ W_a + b_a), h_b = relu(x_b @ W_b + b_b)
//   A = scatter(edge_ab) [Na,Nb], B = scatter(edge_ba) [Nb,Na]
//   deg = colcount(A) + rowcount(B); d = 1/deg (0 where deg==0)
// 4-kernel pipeline:
//   K1 w_prep:     zero counters + W -> MFMA fragment layout
//   K2 edges_gemm: fat kernel = {dual MFMA projection} U {edge bucketize}
//   K3 gather (norm): u = d * (B @ h_a) + h_b
//   K4 gather:        out = A @ u
// Bucketed adjacency (capacity 256/row) replaces count->scan->fill CSR.

#define D_FEAT 128
#define F_IN 512
#define BCAP 256

using short8 = __attribute__((ext_vector_type(8))) short;
using f32x4  = __attribute__((ext_vector_type(4))) float;

__device__ inline short f2bf(float f) {
    unsigned u = __builtin_bit_cast(unsigned, f);
    unsigned r = (u + 0x7FFFu + ((u >> 16) & 1u)) >> 16;
    return (short)r;
}

// ---------------- K1: W pre-swizzle into MFMA B-fragment layout + counter zero
// Wf layout: [t=0..15][c=0..7][lane=0..63][e=0..7] (shorts), where
//   k = t*32 + (lane>>4)*8 + e, col = c*16 + (lane&15)
__global__ __launch_bounds__(256) void w_prep(
    const float* __restrict__ Wa, const float* __restrict__ Wb,
    short* __restrict__ WfA, short* __restrict__ WfB,
    int* __restrict__ zero_region, int zero_n) {
    int g = blockIdx.x * 256 + threadIdx.x;  // 0..16383
    for (int z = g; z < zero_n; z += 16384) zero_region[z] = 0;
    const float* W = (g < 8192) ? Wa : Wb;
    short* Wf = (g < 8192) ? WfA : WfB;
    int i = g & 8191;
    int l = i & 63;
    int c = (i >> 6) & 7;
    int t = i >> 9;  // 0..15
    int col = c * 16 + (l & 15);
    int kbase = t * 32 + (l >> 4) * 8;
    short8 o;
#pragma unroll
    for (int e = 0; e < 8; ++e) o[e] = f2bf(W[(size_t)(kbase + e) * D_FEAT + col]);
    *(short8*)(Wf + (size_t)i * 8) = o;
}

// ---------------- K2: fat kernel = dual MFMA GEMM + edge bucketize ----------
// blocks [0, nblk_a+nblk_b): projection h = relu(x @ W + b), 16 rows/block,
//   4 waves K-split, LDS cross-wave reduce (stride 132), bias+relu epilogue.
// blocks [nblk_a+nblk_b, +nEdgeBlk): one thread per edge; bucket insert +
//   degree counts. Independent of the GEMM half; both depend only on K1.
__global__ __launch_bounds__(256) void edges_gemm(
    const float* __restrict__ xa, const short* __restrict__ Wfa,
    const float* __restrict__ ba_, float* __restrict__ ha,
    const float* __restrict__ xb, const short* __restrict__ Wfb,
    const float* __restrict__ bb_, float* __restrict__ hb, int nblk_a, int nblk_g,
    const int* __restrict__ ab_row, const int* __restrict__ ab_col,
    const int* __restrict__ ba_row, const int* __restrict__ ba_col,
    int* __restrict__ cnt_ab, int* __restrict__ cnt_ba, int* __restrict__ degc,
    int* __restrict__ buck_ab, int* __restrict__ buck_ba, int Eab, int Eba) {
    int blk = blockIdx.x;
    if (blk >= nblk_g) {
        // ---- edge bucketize half ----
        int g = (blk - nblk_g) * 256 + threadIdx.x;
        if (g < Eab) {
            int r = ab_row[g], c = ab_col[g];
            int p = atomicAdd(&cnt_ab[r], 1);
            if (p < BCAP) buck_ab[(size_t)r * BCAP + p] = c;
            atomicAdd(&degc[c], 1);
        } else if (g < Eab + Eba) {
            int e = g - Eab;
            int r = ba_row[e], c = ba_col[e];
            int p = atomicAdd(&cnt_ba[r], 1);
            if (p < BCAP) buck_ba[(size_t)r * BCAP + p] = c;
        }
        return;
    }
    // ---- MFMA projection half ----
    const float* x; const short* Wf; const float* bias; float* h;
    if (blk < nblk_a) { x = xa; Wf = Wfa; bias = ba_; h = ha; }
    else { blk -= nblk_a; x = xb; Wf = Wfb; bias = bb_; h = hb; }
    const int row0 = blk * 16;
    const int tid = threadIdx.x;
    const int w = tid >> 6;
    const int l = tid & 63;
    const int lr = l & 15;   // A-row / C-col within tile
    const int lk = l >> 4;   // k-subgroup / C-row-group

    f32x4 acc[8];
#pragma unroll
    for (int c = 0; c < 8; ++c) acc[c] = (f32x4){0.f, 0.f, 0.f, 0.f};

    const float* xrow = x + (size_t)(row0 + lr) * F_IN;
#pragma unroll
    for (int ks = 0; ks < 4; ++ks) {
        const int t = w * 4 + ks;
        const int k0 = t * 32 + lk * 8;
        float4 xf0 = *(const float4*)(xrow + k0);
        float4 xf1 = *(const float4*)(xrow + k0 + 4);
        short8 afr;
        afr[0] = f2bf(xf0.x); afr[1] = f2bf(xf0.y);
        afr[2] = f2bf(xf0.z); afr[3] = f2bf(xf0.w);
        afr[4] = f2bf(xf1.x); afr[5] = f2bf(xf1.y);
        afr[6] = f2bf(xf1.z); afr[7] = f2bf(xf1.w);
        const short8* wfp = (const short8*)Wf + ((size_t)t * 8 * 64 + l);
#pragma unroll
        for (int c = 0; c < 8; ++c) {
            short8 bfr = wfp[c * 64];
            acc[c] = __builtin_amdgcn_mfma_f32_16x16x32_bf16(afr, bfr, acc[c], 0, 0, 0);
        }
    }

    __shared__ float red[4][16][132];
#pragma unroll
    for (int c = 0; c < 8; ++c)
#pragma unroll
        for (int r = 0; r < 4; ++r)
            red[w][lk * 4 + r][c * 16 + lr] = acc[c][r];
    __syncthreads();

#pragma unroll
    for (int q = 0; q < 2; ++q) {
        int fi = tid * 2 + q;          // 0..511
        int r = fi >> 5;               // 0..15
        int c4 = fi & 31;              // float4 col index
        float4 s0 = *(const float4*)&red[0][r][c4 * 4];
        float4 s1 = *(const float4*)&red[1][r][c4 * 4];
        float4 s2 = *(const float4*)&red[2][r][c4 * 4];
        float4 s3 = *(const float4*)&red[3][r][c4 * 4];
        float4 bv = ((const float4*)bias)[c4];
        float4 o;
        o.x = fmaxf(s0.x + s1.x + s2.x + s3.x + bv.x, 0.0f);
        o.y = fmaxf(s0.y + s1.y + s2.y + s3.y + bv.y, 0.0f);
        o.z = fmaxf(s0.z + s1.z + s2.z + s3.z + bv.z, 0.0f);
        o.w = fmaxf(s0.w + s1.w + s2.w + s3.w + bv.w, 0.0f);
        ((float4*)(h + (size_t)(row0 + r) * D_FEAT))[c4] = o;
    }
}

// ---------------- gather-reduce over buckets: dst[r] = sum src[buck[r][..]] --
// one 64-lane wave per row, float2 per lane, 8-deep unroll; norm epilogue:
//   dst[r] = acc * (1/deg[r] or 0) + addv[r]
__global__ __launch_bounds__(256) void gather_rows(
    const int* __restrict__ cnt, const int* __restrict__ buck,
    const float* __restrict__ src,
    float* __restrict__ dst, const float* __restrict__ addv,
    const int* __restrict__ dg0, const int* __restrict__ dg1,
    int Nrow, int norm) {
    int w = threadIdx.x >> 6;
    int lane = threadIdx.x & 63;
    int r = blockIdx.x * 4 + w;
    if (r >= Nrow) return;
    int n = cnt[r];
    if (n > BCAP) n = BCAP;
    const int* cols = buck + (size_t)r * BCAP;
    const float2* s2 = (const float2*)src;
    float ax = 0.0f, ay = 0.0f;
    int e = 0;
    for (; e + 7 < n; e += 8) {
        int c0 = cols[e],     c1 = cols[e + 1], c2 = cols[e + 2], c3 = cols[e + 3];
        int c4 = cols[e + 4], c5 = cols[e + 5], c6 = cols[e + 6], c7 = cols[e + 7];
        float2 v0 = s2[(size_t)c0 * 64 + lane];
        float2 v1 = s2[(size_t)c1 * 64 + lane];
        float2 v2 = s2[(size_t)c2 * 64 + lane];
        float2 v3 = s2[(size_t)c3 * 64 + lane];
        float2 v4 = s2[(size_t)c4 * 64 + lane];
        float2 v5 = s2[(size_t)c5 * 64 + lane];
        float2 v6 = s2[(size_t)c6 * 64 + lane];
        float2 v7 = s2[(size_t)c7 * 64 + lane];
        ax += (v0.x + v1.x) + (v2.x + v3.x) + ((v4.x + v5.x) + (v6.x + v7.x));
        ay += (v0.y + v1.y) + (v2.y + v3.y) + ((v4.y + v5.y) + (v6.y + v7.y));
    }
    for (; e < n; ++e) {
        int c = cols[e];
        float2 v = s2[(size_t)c * 64 + lane];
        ax += v.x; ay += v.y;
    }
    if (norm) {
        float dgf = (float)(dg0[r] + dg1[r]);
        float inv = dgf > 0.0f ? 1.0f / dgf : 0.0f;
        float2 hbv = ((const float2*)addv)[(size_t)r * 64 + lane];
        ax = ax * inv + hbv.x;
        ay = ay * inv + hbv.y;
    }
    float2 o; o.x = ax; o.y = ay;
    ((float2*)dst)[(size_t)r * 64 + lane] = o;
}

extern "C" void kernel_launch(void* const* d_in, const int* in_sizes, int n_in,
                              void* d_out, int out_size, void* d_ws, size_t ws_size,
                              hipStream_t stream) {
    const float* x_a = (const float*)d_in[0];
    const float* x_b = (const float*)d_in[1];
    const float* W_a = (const float*)d_in[2];
    const float* b_a = (const float*)d_in[3];
    const float* W_b = (const float*)d_in[4];
    const float* b_b = (const float*)d_in[5];
    const int* ei_ab = (const int*)d_in[6];
    const int* ei_ba = (const int*)d_in[7];

    const int D = in_sizes[3];            // 128
    const int Fa = in_sizes[2] / D;       // 512
    const int Na = in_sizes[0] / Fa;      // 4096
    const int Fb = in_sizes[4] / D;       // 512
    const int Nb = in_sizes[1] / Fb;      // 4096
    const int Eab = in_sizes[6] / 2;      // 131072
    const int Eba = in_sizes[7] / 2;      // 131072

    const int* ab_row = ei_ab;
    const int* ab_col = ei_ab + Eab;
    const int* ba_row = ei_ba;
    const int* ba_col = ei_ba + Eba;

    // ---- workspace layout ----
    char* p = (char*)d_ws;
    float* h_a = (float*)p; p += (size_t)Na * D * 4;
    float* h_b = (float*)p; p += (size_t)Nb * D * 4;
    float* u   = (float*)p; p += (size_t)Nb * D * 4;
    int* buck_ab = (int*)p; p += (size_t)Na * BCAP * 4;   // 4 MB
    int* buck_ba = (int*)p; p += (size_t)Nb * BCAP * 4;   // 4 MB
    short* WfA = (short*)p; p += (size_t)Fa * D * 2;      // 128 KB
    short* WfB = (short*)p; p += (size_t)Fb * D * 2;
    // zeroed region (by w_prep): cnt_ab, cnt_ba, degc (contiguous)
    int* cnt_ab = (int*)p; p += (size_t)Na * 4;
    int* cnt_ba = (int*)p; p += (size_t)Nb * 4;
    int* degc   = (int*)p; p += (size_t)Nb * 4;

    float* out = (float*)d_out;

    // K1: W -> fragment layout + zero counters
    w_prep<<<64, 256, 0, stream>>>(W_a, W_b, WfA, WfB, cnt_ab, Na + 2 * Nb);

    // K2: fat kernel — projections (blocks 0..nblk_g) + edge bucketize
    int nblk_a = Na / 16, nblk_b = Nb / 16;
    int nblk_g = nblk_a + nblk_b;
    int nEdgeBlk = (Eab + Eba + 255) / 256;
    edges_gemm<<<nblk_g + nEdgeBlk, 256, 0, stream>>>(
        x_a, WfA, b_a, h_a, x_b, WfB, b_b, h_b, nblk_a, nblk_g,
        ab_row, ab_col, ba_row, ba_col,
        cnt_ab, cnt_ba, degc, buck_ab, buck_ba, Eab, Eba);

    // K3: u = d * (B @ h_a) + h_b
    gather_rows<<<(Nb + 3) / 4, 256, 0, stream>>>(cnt_ba, buck_ba, h_a, u,
                                                  h_b, degc, cnt_ba, Nb, 1);
    // K4: out = A @ u
    gather_rows<<<(Na + 3) / 4, 256, 0, stream>>>(cnt_ab, buck_ab, u, out,
                                                  (const float*)nullptr,
                                                  (const int*)nullptr, (const int*)nullptr,
                                                  Na, 0);
}